// Round 1
// 432.876 us; speedup vs baseline: 1.1140x; 1.1140x over previous
//
#include <hip/hip_runtime.h>
#include <hip/hip_bf16.h>
#include <cstdint>

#define B_SZ 8192
#define NH 16
#define HD 256
#define FH 512
#define BR 64            // batch rows per ffn block

typedef __bf16 bf16x8 __attribute__((ext_vector_type(8)));
typedef float f32x4 __attribute__((ext_vector_type(4)));

#define VMCNT(n) asm volatile("s_waitcnt vmcnt(" #n ")" ::: "memory")
#define LGKM0()  asm volatile("s_waitcnt lgkmcnt(0)" ::: "memory")
#define MEMFENCE() asm volatile("" ::: "memory")

// async global->LDS, 16 bytes per lane. lds base must be wave-uniform;
// lane i's data lands at lds_base + i*16.
__device__ __forceinline__ void lds_load16(const void* g, void* l) {
  __builtin_amdgcn_global_load_lds(
      (const __attribute__((address_space(1))) unsigned char*)g,
      (__attribute__((address_space(3))) unsigned char*)l, 16, 0, 0);
}

// ---------------- weight convert + transpose (all 3 weights in one launch):
// src fp32 [NH][K][N] -> dst bf16 [NH][N][K]
__global__ __launch_bounds__(256) void wcvt_kernel(const float* __restrict__ w1,
                                                   const float* __restrict__ w3,
                                                   const float* __restrict__ w2,
                                                   __bf16* __restrict__ w1t,
                                                   __bf16* __restrict__ w3t,
                                                   __bf16* __restrict__ w2t) {
  int bid = blockIdx.x;
  const float* src;
  __bf16* dst;
  int K, N;
  if (bid < 2048)      { src = w1; dst = w1t; K = 256; N = 512; }
  else if (bid < 4096) { src = w3; dst = w3t; K = 256; N = 512; bid -= 2048; }
  else                 { src = w2; dst = w2t; K = 512; N = 256; bid -= 4096; }
  const int tiles_n = N >> 5, tiles_k = K >> 5;
  const int per_head = tiles_n * tiles_k;
  const int head = bid / per_head;
  const int rem = bid - head * per_head;
  const int tk = rem / tiles_n;
  const int tn = rem - tk * tiles_n;
  __shared__ float tile[32][33];
  const float* s = src + ((size_t)head * K + tk * 32) * N + tn * 32;
  const int r = threadIdx.x >> 3;           // 0..31
  const int c4 = (threadIdx.x & 7) * 4;     // 0..28
  float4 v = *(const float4*)(s + (size_t)r * N + c4);
  tile[r][c4 + 0] = v.x; tile[r][c4 + 1] = v.y;
  tile[r][c4 + 2] = v.z; tile[r][c4 + 3] = v.w;
  __syncthreads();
  __bf16 o[4] __attribute__((aligned(8)));
  #pragma unroll
  for (int j = 0; j < 4; ++j) o[j] = (__bf16)tile[c4 + j][r];
  __bf16* d = dst + ((size_t)head * N + tn * 32 + r) * K + tk * 32 + c4;
  *(uint2*)d = *(uint2*)o;
}

// ---------------- prep: rmsnorm1 -> head-mix -> mask -> +x = p ; rmsnorm2 -> h
// 8 rows per block. p_ws: bf16 [NH][B][HD]   h_ws: bf16 [NH][B][HD]
#define PREP_R 8
__global__ __launch_bounds__(256) void prep_kernel(const float* __restrict__ x,
                                                   const float* __restrict__ n1w,
                                                   const float* __restrict__ n2w,
                                                   const float* __restrict__ mask,
                                                   __bf16* __restrict__ p_ws,
                                                   __bf16* __restrict__ h_ws) {
  const int t = threadIdx.x;
  const int g = t >> 4;     // head this thread produces
  const int li = t & 15;    // sub-block / source head index
  __shared__ float xs[16 * 260];
  __shared__ float rms1s[16];

  // invariant per-thread parameter caches
  float n1c[16], n2c[16], mc[16];
  #pragma unroll
  for (int j = 0; j < 4; ++j) {
    *(float4*)(n1c + j * 4) = *(const float4*)(n1w + g * 16 + j * 4);
    *(float4*)(n2c + j * 4) = *(const float4*)(n2w + li * 16 + j * 4);
    *(float4*)(mc + j * 4)  = *(const float4*)(mask + g * HD + li * 16 + j * 4);
  }

  for (int r = 0; r < PREP_R; ++r) {
    const int b = blockIdx.x * PREP_R + r;
    const float* xb = x + (size_t)b * (NH * HD);
    if (r) __syncthreads();   // xs free from previous row

    float xv[16];
    float ss = 0.f;
    #pragma unroll
    for (int j = 0; j < 4; ++j) {
      float4 v = *(const float4*)(xb + g * HD + li * 16 + j * 4);
      *(float4*)(xs + g * 260 + li * 16 + j * 4) = v;
      xv[j * 4 + 0] = v.x; xv[j * 4 + 1] = v.y;
      xv[j * 4 + 2] = v.z; xv[j * 4 + 3] = v.w;
      ss += v.x * v.x + v.y * v.y + v.z * v.z + v.w * v.w;
    }
    #pragma unroll
    for (int d = 1; d < 16; d <<= 1) ss += __shfl_xor(ss, d);
    if (li == 0) rms1s[g] = rsqrtf(ss * (1.f / 256.f) + 1e-6f);
    __syncthreads();

    const float r1 = rms1s[li];
    float pv[16];
    float ss2 = 0.f;
    #pragma unroll
    for (int j = 0; j < 4; ++j) {
      float4 sv = *(const float4*)(xs + li * 260 + g * 16 + j * 4);
      float s4[4] = {sv.x, sv.y, sv.z, sv.w};
      #pragma unroll
      for (int q = 0; q < 4; ++q) {
        const int k = j * 4 + q;
        const float mixed = s4[q] * r1 * n1c[k] * mc[k];
        const float p = mixed + xv[k];
        pv[k] = p;
        ss2 += p * p;
      }
    }
    #pragma unroll
    for (int d = 1; d < 16; d <<= 1) ss2 += __shfl_xor(ss2, d);
    const float r2 = rsqrtf(ss2 * (1.f / 256.f) + 1e-6f);

    __bf16 pb[16] __attribute__((aligned(16)));
    __bf16 hv[16] __attribute__((aligned(16)));
    #pragma unroll
    for (int k = 0; k < 16; ++k) {
      pb[k] = (__bf16)pv[k];
      hv[k] = (__bf16)(pv[k] * r2 * n2c[k]);
    }
    __bf16* pp = p_ws + ((size_t)g * B_SZ + b) * HD + li * 16;
    *(uint4*)(pp + 0) = *(uint4*)(pb + 0);
    *(uint4*)(pp + 8) = *(uint4*)(pb + 8);
    __bf16* hp = h_ws + ((size_t)g * B_SZ + b) * HD + li * 16;
    *(uint4*)(hp + 0) = *(uint4*)(hv + 0);
    *(uint4*)(hp + 8) = *(uint4*)(hv + 8);
  }
}

// ---------------- fused FFN v3: out = (silu(H W1) * (H W3)) W2 + p
// Counted-vmcnt ring pipeline (T3+T4+T5). Per hc: 6 uniform stages of
// 4 global_load_lds/lane ping-pong across two 16KB Wbuf slots. All weight
// staging is wave-byte-private (stage1 and stage2 deliberately share the
// SAME per-wave byte regions), so NO barriers guard Wbuf — only each wave's
// own s_waitcnt vmcnt(4). The only cross-wave barriers are the Sc publish
// (silu->stage2) and Sc WAR (stage2->next silu): 2 raw s_barriers per hc
// (vs 13 __syncthreads = vmcnt(0) drains before).
__global__ __launch_bounds__(256, 2) void ffn_kernel(const __bf16* __restrict__ h_ws,
                                                     const __bf16* __restrict__ w1t,
                                                     const __bf16* __restrict__ w3t,
                                                     const __bf16* __restrict__ w2t,
                                                     const __bf16* __restrict__ p_ws,
                                                     float* __restrict__ out) {
  const int bid = blockIdx.x;
  const int head = bid & 15;            // head pinned to XCD bid%8 (2 heads/XCD)
  const int stripe = bid >> 4;          // 0..127
  const int r0 = stripe * BR;
  const int t = threadIdx.x;
  const int wv = t >> 6, lane = t & 63;
  const int mlane = lane & 15, quad = lane >> 4;

  __shared__ __bf16 __attribute__((aligned(16))) Hs[BR * HD];    // 32 KB [row][k], chunk c holds global c^(row&15)
  __shared__ __bf16 __attribute__((aligned(16))) Wbuf[16384];    // 32 KB = 2 slots x 16 KB (ring)
  __shared__ __bf16 __attribute__((aligned(16))) Sc[BR * 64];    //  8 KB [row][hid], chunk c holds global c^(row&7)

  const __bf16* W1h = w1t + (size_t)head * FH * HD;
  const __bf16* W3h = w3t + (size_t)head * FH * HD;
  const __bf16* W2h = w2t + (size_t)head * HD * FH;

  // ---- stage issue helpers (4 DMA loads/lane each; all wave-byte-private) ----
  // stage1 (W1+W3, hid rows wv*16..+15, k-chunk kk*64..+63):
  //   wave bytes: slot[wv*2048..+2048) (W1) + slot[8192+wv*2048..+2048) (W3)
  auto stage1_issue = [&](__bf16* Ws, int hc, int kk) {
    const int rl = lane >> 3, c = lane & 7, gch = c ^ rl;
    #pragma unroll
    for (int i = 0; i < 2; ++i) {
      const int rb = wv * 16 + i * 8;
      const size_t go = (size_t)(hc * 64 + rb + rl) * HD + kk * 64 + gch * 8;
      lds_load16(W1h + go, Ws + rb * 64);
      lds_load16(W3h + go, Ws + 4096 + rb * 64);
    }
  };
  // stage2 (W2, out rows wv*64..+63, k-chunk hc*64+ks*32..+31), split into two
  // 8KB halves so wave byte regions coincide exactly with stage1's:
  //   half h: slot[h*8192 + wv*2048 ..+2048)  (rows wv*64+h*32..+31, 64B/row)
  auto stage2_issue = [&](__bf16* Ws, int hc, int ks) {
    const int rl = lane >> 2, c = lane & 3, gch = c ^ (rl & 3);
    #pragma unroll
    for (int i = 0; i < 4; ++i) {
      const int rb = wv * 64 + i * 16;
      lds_load16(W2h + (size_t)(rb + rl) * FH + hc * 64 + ks * 32 + gch * 8,
                 Ws + (i >> 1) * 4096 + wv * 1024 + (i & 1) * 512);
    }
  };

  // ---- prologue: stage Hs (8 loads/wave), then prefetch s1k0/s1k1 of hc=0
  const __bf16* Hb = h_ws + ((size_t)head * B_SZ + r0) * HD;
  {
    const int rloc = lane >> 5;       // 0/1
    const int ch = lane & 31;
    #pragma unroll
    for (int i = 0; i < 8; ++i) {
      const int row = wv * 16 + i * 2 + rloc;
      const int gch = ch ^ (row & 15);
      lds_load16(Hb + (size_t)row * HD + gch * 8, Hs + (wv * 16 + i * 2) * HD);
    }
  }
  MEMFENCE();                       // keep Hs DMAs ordered before prefetches
  stage1_issue(Wbuf, 0, 0);
  stage1_issue(Wbuf + 8192, 0, 1);
  VMCNT(8);                         // own 8 Hs loads done (8 prefetches in flight)
  __builtin_amdgcn_s_barrier();     // Hs visible to all waves (read-only after)

  f32x4 oacc[4][4];
  #pragma unroll
  for (int mt = 0; mt < 4; ++mt)
    #pragma unroll
    for (int nt = 0; nt < 4; ++nt) oacc[mt][nt] = (f32x4){0.f, 0.f, 0.f, 0.f};

  for (int hc = 0; hc < 8; ++hc) {
    // ================= stage 1: g/v[64 hid chunk][64 rows], K=256 =================
    f32x4 g[4], v[4];
    #pragma unroll
    for (int nt = 0; nt < 4; ++nt) {
      g[nt] = (f32x4){0.f, 0.f, 0.f, 0.f};
      v[nt] = (f32x4){0.f, 0.f, 0.f, 0.f};
    }
    #pragma unroll
    for (int kk = 0; kk < 4; ++kk) {
      __bf16* Ws = Wbuf + (kk & 1) * 8192;
      VMCNT(4);                     // own slot loads done; next stage in flight
      #pragma unroll
      for (int ks = 0; ks < 2; ++ks) {
        const int ar = wv * 16 + mlane;            // wave-private hid row
        const int ach = (ks * 4 + quad) ^ (ar & 7);
        bf16x8 a1 = *(const bf16x8*)(Ws + ar * 64 + ach * 8);
        bf16x8 a3 = *(const bf16x8*)(Ws + 4096 + ar * 64 + ach * 8);
        const int gk = kk * 8 + ks * 4 + quad;     // global 8-elem k-chunk
        bf16x8 b[4];
        #pragma unroll
        for (int nt = 0; nt < 4; ++nt) {
          const int row = nt * 16 + mlane;
          b[nt] = *(const bf16x8*)(Hs + row * HD + (gk ^ (row & 15)) * 8);
        }
        if (ks == 1) {
          LGKM0();                  // this wave's slot reads retired -> safe to overwrite
          if (kk < 2) stage1_issue(Ws, hc, kk + 2);
          else        stage2_issue(Ws, hc, kk - 2);
        }
        __builtin_amdgcn_s_setprio(1);
        #pragma unroll
        for (int nt = 0; nt < 4; ++nt) {
          g[nt] = __builtin_amdgcn_mfma_f32_16x16x32_bf16(a1, b[nt], g[nt], 0, 0, 0);
          v[nt] = __builtin_amdgcn_mfma_f32_16x16x32_bf16(a3, b[nt], v[nt], 0, 0, 0);
        }
        __builtin_amdgcn_s_setprio(0);
      }
    }

    // ---- silu -> Sc
    #pragma unroll
    for (int nt = 0; nt < 4; ++nt) {
      const int row = nt * 16 + mlane;
      __bf16 sv[4] __attribute__((aligned(8)));
      #pragma unroll
      for (int r = 0; r < 4; ++r) {
        const float gg = g[nt][r];
        sv[r] = (__bf16)(gg / (1.f + __expf(-gg)) * v[nt][r]);
      }
      const int boff = wv * 32 + quad * 8;          // byte offset of hid-local in row
      const int ph = ((boff >> 4) ^ (row & 7));
      char* dst = (char*)Sc + row * 128 + ph * 16 + (boff & 15);
      *(uint2*)dst = *(uint2*)sv;
    }
    LGKM0();
    __builtin_amdgcn_s_barrier();   // BARRIER_A: Sc published (counted vmcnt untouched)

    // ================= stage 2: oacc += W2[:, hc*64..+64] * Sc =================
    const int hcn = (hc + 1) & 7;   // hc=7 issues dummy hc=0 prefetches (keeps vmcnt math uniform)
    #pragma unroll
    for (int ks = 0; ks < 2; ++ks) {
      __bf16* Ws = Wbuf + (ks & 1) * 8192;
      VMCNT(4);                     // own W2 chunk done; other stage in flight
      bf16x8 a2[4], b2[4];
      #pragma unroll
      for (int mt = 0; mt < 4; ++mt)
        a2[mt] = *(const bf16x8*)(Ws + (mt >> 1) * 4096 + wv * 1024 + (mt & 1) * 512
                                  + mlane * 32 + ((quad ^ (mlane & 3))) * 8);
      #pragma unroll
      for (int nt = 0; nt < 4; ++nt) {
        const int row = nt * 16 + mlane;
        b2[nt] = *(const bf16x8*)(Sc + row * 64 + (((ks * 4 + quad) ^ (row & 7))) * 8);
      }
      LGKM0();                      // Sc + slot reads retired
      stage1_issue(Ws, hcn, ks);    // prefetch next hc's s1k0/s1k1
      if (ks == 1) __builtin_amdgcn_s_barrier();  // BARRIER_B: Sc WAR before next silu
      __builtin_amdgcn_s_setprio(1);
      #pragma unroll
      for (int mt = 0; mt < 4; ++mt)
        #pragma unroll
        for (int nt = 0; nt < 4; ++nt)
          oacc[mt][nt] = __builtin_amdgcn_mfma_f32_16x16x32_bf16(a2[mt], b2[nt], oacc[mt][nt], 0, 0, 0);
      __builtin_amdgcn_s_setprio(0);
    }
  }

  VMCNT(0);   // drain dummy prefetches: no DMA may outlive this block's LDS

  // ---- epilogue: out[b][head*256+oc] = oacc + p
  const __bf16* Pb = p_ws + ((size_t)head * B_SZ + r0) * HD;
  float* Ob = out + (size_t)r0 * (NH * HD) + head * HD;
  #pragma unroll
  for (int mt = 0; mt < 4; ++mt)
    #pragma unroll
    for (int nt = 0; nt < 4; ++nt) {
      const int row = nt * 16 + mlane;
      const int oc = wv * 64 + mt * 16 + quad * 4;
      __bf16 pv[4] __attribute__((aligned(8)));
      *(uint2*)pv = *(const uint2*)(Pb + (size_t)row * HD + oc);
      float4 o;
      o.x = oacc[mt][nt][0] + (float)pv[0];
      o.y = oacc[mt][nt][1] + (float)pv[1];
      o.z = oacc[mt][nt][2] + (float)pv[2];
      o.w = oacc[mt][nt][3] + (float)pv[3];
      *(float4*)(Ob + (size_t)row * (NH * HD) + oc) = o;
    }
}

extern "C" void kernel_launch(void* const* d_in, const int* in_sizes, int n_in,
                              void* d_out, int out_size, void* d_ws, size_t ws_size,
                              hipStream_t stream) {
  const float* x    = (const float*)d_in[0];
  const float* n1w  = (const float*)d_in[1];
  const float* n2w  = (const float*)d_in[2];
  const float* w1   = (const float*)d_in[3];
  const float* w3   = (const float*)d_in[4];
  const float* w2   = (const float*)d_in[5];
  const float* mask = (const float*)d_in[6];
  float* out = (float*)d_out;

  char* ws = (char*)d_ws;
  // ws layout (bytes):
  //   p_ws  bf16 [16][8192][256]  @ 0          (67108864)
  //   h_ws  bf16 [16][8192][256]  @ 67108864   (67108864)
  //   w1t   bf16 [16][512][256]   @ 134217728  ( 4194304)
  //   w3t   bf16 [16][512][256]   @ 138412032  ( 4194304)
  //   w2t   bf16 [16][256][512]   @ 142606336  ( 4194304)
  __bf16* p_ws = (__bf16*)(ws + 0);
  __bf16* h_ws = (__bf16*)(ws + 67108864);
  __bf16* w1t  = (__bf16*)(ws + 134217728);
  __bf16* w3t  = (__bf16*)(ws + 138412032);
  __bf16* w2t  = (__bf16*)(ws + 142606336);

  wcvt_kernel<<<6144, 256, 0, stream>>>(w1, w3, w2, w1t, w3t, w2t);
  prep_kernel<<<1024, 256, 0, stream>>>(x, n1w, n2w, mask, p_ws, h_ws);
  ffn_kernel<<<2048, 256, 0, stream>>>(h_ws, w1t, w3t, w2t, p_ws, out);
}